// Round 4
// baseline (138.961 us; speedup 1.0000x reference)
//
#include <hip/hip_runtime.h>

// NestedConv via MFMA bf16: B=64, N=128, D=64.
// out[b,i,j,:] = m[b,i,j] * sum_k A[b,k,j] * h[b,i,k,:]
// h = relu(relu((m*X)@W1+b1)@W2+b2),  A symmetric 0/1 (bf16-exact).
//
// Round-4 restructure (operand-swapped MFMA phases):
//  - layer 1: H1T-tile = mfma(W1T-frag, XmT-frag); X fragments loaded DIRECTLY
//    from global (X has zero intra-block reuse -> LDS staging was pure cost);
//    C-layout gives 4 consecutive d at fixed r -> vectorized 8B H1[r][d] write.
//  - layer 2 reads H1 rows written by the SAME wave -> no barrier after L1.
//  - phase 2: outT-tile = mfma(H2T-frag, Apk-frag) (A symmetric -> Apk is a
//    valid B-operand); C gives 4 consecutive d at fixed j -> float4 out stores.
//  - exactly ONE __syncthreads (H2T is read cross-wave).
#define Bv 64
#define Nv 128
#define Dv 64

// ws layout: [0,32KB): Wpk (16KB used). [32KB, 32KB+2MB): Apk.
#define APK_OFF_SH 16384
#define WS_NEED (32768 + Bv * 32768)

typedef __attribute__((ext_vector_type(8))) short bf16x8;
typedef __attribute__((ext_vector_type(4))) float f32x4;

__device__ __forceinline__ unsigned short f2bf(float f) {
    unsigned u = __float_as_uint(f);
    u += 0x7FFFu + ((u >> 16) & 1u);
    return (unsigned short)(u >> 16);
}
__device__ __forceinline__ unsigned pk2(float a, float b) {
    return (unsigned)f2bf(a) | ((unsigned)f2bf(b) << 16);
}
__device__ __forceinline__ bf16x8 pack8m(float4 a, float4 b, float m) {
    bf16x8 r;
    r[0] = (short)f2bf(m * a.x); r[1] = (short)f2bf(m * a.y);
    r[2] = (short)f2bf(m * a.z); r[3] = (short)f2bf(m * a.w);
    r[4] = (short)f2bf(m * b.x); r[5] = (short)f2bf(m * b.y);
    r[6] = (short)f2bf(m * b.z); r[7] = (short)f2bf(m * b.w);
    return r;
}
__device__ __forceinline__ bf16x8 pack8(float4 a, float4 b) {
    return pack8m(a, b, 1.0f);
}
// fallback W fragment loader: 8 strided scalar loads (PRE=false only)
__device__ __forceinline__ bf16x8 load_w_frag(const float* __restrict__ W,
                                              int kkbase, int dn, int l15, int l16) {
    const float* p = W + (kkbase + 8 * l16) * Dv + dn + l15;
    bf16x8 r;
    #pragma unroll
    for (int t = 0; t < 8; ++t) r[t] = (short)f2bf(p[t * Dv]);
    return r;
}

// ---- pre-kernel: pack W1,W2 fragments ----
// Wpk[f][l][t], f = layer*8 + kk*4 + tn; value = W[kk*32+8*(l>>4)+t][tn*16+(l&15)]
// (serves as B-operand of W and as A-operand of W^T — same lane data)
__global__ void pack_w_kernel(const float* __restrict__ W1,
                              const float* __restrict__ W2,
                              unsigned short* __restrict__ wpk) {
    const int idx = blockIdx.x * 256 + threadIdx.x;   // 1024 items
    const int l = idx & 63, f = idx >> 6;             // f = 0..15
    const int layer = f >> 3, kk = (f >> 2) & 1, tn = f & 3;
    const float* W = layer ? W2 : W1;
    const float* p = W + (kk * 32 + 8 * (l >> 4)) * Dv + tn * 16 + (l & 15);
    unsigned short* o = wpk + f * 512 + l * 8;
    #pragma unroll
    for (int t = 0; t < 8; ++t) o[t] = f2bf(p[t * Dv]);
}

// ---- pre-kernel: pack A fragments ----
// Apk[b][jt][kk][l][t] = A[b][jt*16+(l&15)][kk*32+8*(l>>4)+t]
__global__ void pack_a_kernel(const float* __restrict__ A,
                              unsigned short* __restrict__ apk) {
    const int gid = blockIdx.x * 256 + threadIdx.x;   // 131072 items
    const int l = gid & 63, f = gid >> 6;             // f = b*32 + jt*4 + kk
    const int b = f >> 5, r = f & 31, jt = r >> 2, kk = r & 3;
    const float4* p = (const float4*)(A +
        ((size_t)(b * Nv + jt * 16 + (l & 15))) * Nv + kk * 32 + 8 * (l >> 4));
    *(bf16x8*)(apk + (size_t)f * 512 + l * 8) = pack8(p[0], p[1]);
}

template <bool PRE>
__global__ __launch_bounds__(256, 4)
void nested_conv_mfma(const float* __restrict__ X,
                      const float* __restrict__ A,
                      const int*   __restrict__ mask,
                      const float* __restrict__ W1,
                      const float* __restrict__ b1,
                      const float* __restrict__ W2,
                      const float* __restrict__ b2,
                      const unsigned short* __restrict__ wpk,
                      const unsigned short* __restrict__ apk,
                      float* __restrict__ out)
{
    __shared__ __align__(16) unsigned char H1[16384];   // [128 r][64 d] bf16, swizzled
    __shared__ __align__(16) unsigned char H2T[16384];  // [64 d][128 k] bf16, swizzled

    const int i = blockIdx.x, b = blockIdx.y;
    const int tid = threadIdx.x;
    const int l   = tid & 63;
    const int w   = tid >> 6;
    const int l15 = l & 15;
    const int l16 = l >> 4;
    const size_t bi = (size_t)(b * Nv + i);

    // ========== layer 1 (swapped): H1T-tiles = W1T @ XmT ==========
    float mmv[2]; const float* xrow[2];
    #pragma unroll
    for (int rr = 0; rr < 2; ++rr) {
        const int r = (2 * w + rr) * 16 + l15;
        mmv[rr]  = mask[bi * Nv + r] ? 1.0f : 0.0f;
        xrow[rr] = X + (bi * Nv + r) * Dv + 8 * l16;
    }
    f32x4 acc1[2][4];
    #pragma unroll
    for (int dt = 0; dt < 4; ++dt) {
        const float4 bv = *(const float4*)&b1[dt * 16 + 4 * l16];
        acc1[0][dt] = (f32x4){bv.x, bv.y, bv.z, bv.w};
        acc1[1][dt] = acc1[0][dt];
    }
    #pragma unroll
    for (int kk = 0; kk < 2; ++kk) {
        bf16x8 xf[2];
        #pragma unroll
        for (int rr = 0; rr < 2; ++rr) {
            const float4* p = (const float4*)(xrow[rr] + kk * 32);
            xf[rr] = pack8m(p[0], p[1], mmv[rr]);
        }
        #pragma unroll
        for (int dt = 0; dt < 4; ++dt) {
            const bf16x8 wf = PRE
                ? *(const bf16x8*)(wpk + (kk * 4 + dt) * 512 + l * 8)
                : load_w_frag(W1, kk * 32, dt * 16, l15, l16);
            acc1[0][dt] = __builtin_amdgcn_mfma_f32_16x16x32_bf16(wf, xf[0], acc1[0][dt], 0, 0, 0);
            acc1[1][dt] = __builtin_amdgcn_mfma_f32_16x16x32_bf16(wf, xf[1], acc1[1][dt], 0, 0, 0);
        }
    }
    // H1[r][d] write: r = (2w+rr)*16+l15, d = dt*16+4*l16+reg -> one 8B write
    #pragma unroll
    for (int rr = 0; rr < 2; ++rr) {
        const int r = (2 * w + rr) * 16 + l15;
        #pragma unroll
        for (int dt = 0; dt < 4; ++dt) {
            const int bo   = dt * 32 + l16 * 8;
            const int addr = r * 128 + (((bo & ~15) ^ ((r & 7) << 4)) | (bo & 15));
            const f32x4 v = acc1[rr][dt];
            *(uint2*)&H1[addr] = make_uint2(pk2(fmaxf(v[0], 0.f), fmaxf(v[1], 0.f)),
                                            pk2(fmaxf(v[2], 0.f), fmaxf(v[3], 0.f)));
        }
    }
    // no barrier: layer 2 reads only this wave's rows (lgkmcnt ordering suffices)

    // ========== layer 2 (normal): H2 = relu(H1 @ W2 + b2) ==========
    f32x4 acc2[2][4];
    #pragma unroll
    for (int tn = 0; tn < 4; ++tn) {
        const float bv = b2[tn * 16 + l15];
        acc2[0][tn] = (f32x4){bv, bv, bv, bv};
        acc2[1][tn] = acc2[0][tn];
    }
    #pragma unroll
    for (int kk = 0; kk < 2; ++kk) {
        bf16x8 af[2];
        #pragma unroll
        for (int rr = 0; rr < 2; ++rr) {
            const int r = (2 * w + rr) * 16 + l15;
            af[rr] = *(const bf16x8*)&H1[r * 128 + ((kk * 64 + 16 * l16) ^ ((r & 7) << 4))];
        }
        #pragma unroll
        for (int tn = 0; tn < 4; ++tn) {
            const bf16x8 wf = PRE
                ? *(const bf16x8*)(wpk + (8 + kk * 4 + tn) * 512 + l * 8)
                : load_w_frag(W2, kk * 32, tn * 16, l15, l16);
            acc2[0][tn] = __builtin_amdgcn_mfma_f32_16x16x32_bf16(af[0], wf, acc2[0][tn], 0, 0, 0);
            acc2[1][tn] = __builtin_amdgcn_mfma_f32_16x16x32_bf16(af[1], wf, acc2[1][tn], 0, 0, 0);
        }
    }
    // H2T[d][k] write: d = tn*16+l15, k = (2w+rr)*16+4*l16+reg -> one 8B write
    #pragma unroll
    for (int rr = 0; rr < 2; ++rr)
        #pragma unroll
        for (int tn = 0; tn < 4; ++tn) {
            const int d  = tn * 16 + l15;
            const int bo = (2 * w + rr) * 32 + l16 * 8;
            const int addr = d * 256 + (((bo & ~15) ^ ((d & 7) << 4)) | (bo & 15));
            const f32x4 v = acc2[rr][tn];
            *(uint2*)&H2T[addr] = make_uint2(pk2(fmaxf(v[0], 0.f), fmaxf(v[1], 0.f)),
                                             pk2(fmaxf(v[2], 0.f), fmaxf(v[3], 0.f)));
        }
    __syncthreads();   // the ONLY barrier: H2T is read cross-wave

    // ========== phase 2 (swapped): outT-tiles = H2T @ A_b ==========
    f32x4 accO[2][4];
    #pragma unroll
    for (int jj = 0; jj < 2; ++jj)
        #pragma unroll
        for (int dt = 0; dt < 4; ++dt)
            accO[jj][dt] = (f32x4){0.f, 0.f, 0.f, 0.f};

    const unsigned short* Apb = apk + (size_t)b * 32 * 512;
    #pragma unroll
    for (int kk = 0; kk < 4; ++kk) {
        bf16x8 anf[2];
        #pragma unroll
        for (int jj = 0; jj < 2; ++jj) {
            const int jt = 2 * w + jj;
            if (PRE) {
                anf[jj] = *(const bf16x8*)(Apb + (jt * 4 + kk) * 512 + l * 8);
            } else {
                const float4* ap = (const float4*)(A +
                    ((size_t)b * Nv + jt * 16 + l15) * Nv + kk * 32 + 8 * l16);
                anf[jj] = pack8(ap[0], ap[1]);
            }
        }
        #pragma unroll
        for (int dt = 0; dt < 4; ++dt) {
            const int d = dt * 16 + l15;
            const bf16x8 hf = *(const bf16x8*)&H2T[d * 256 + ((kk * 64 + 16 * l16) ^ ((d & 7) << 4))];
            accO[0][dt] = __builtin_amdgcn_mfma_f32_16x16x32_bf16(hf, anf[0], accO[0][dt], 0, 0, 0);
            accO[1][dt] = __builtin_amdgcn_mfma_f32_16x16x32_bf16(hf, anf[1], accO[1][dt], 0, 0, 0);
        }
    }

    // ---- out store: outT tile [d][j] -> out[j][d], float4 per (jj,dt) ----
    const int*  mrow = mask + bi * Nv;
    float* Ob = out + bi * Nv * Dv;
    #pragma unroll
    for (int jj = 0; jj < 2; ++jj) {
        const int j = (2 * w + jj) * 16 + l15;
        const float msk = mrow[j] ? 1.0f : 0.0f;
        float* orow = Ob + (size_t)j * Dv + 4 * l16;
        #pragma unroll
        for (int dt = 0; dt < 4; ++dt) {
            const f32x4 v = accO[jj][dt];
            *(float4*)&orow[dt * 16] = make_float4(v[0] * msk, v[1] * msk,
                                                   v[2] * msk, v[3] * msk);
        }
    }
}

extern "C" void kernel_launch(void* const* d_in, const int* in_sizes, int n_in,
                              void* d_out, int out_size, void* d_ws, size_t ws_size,
                              hipStream_t stream) {
    const float* X    = (const float*)d_in[0];
    const float* A    = (const float*)d_in[1];
    const int*   mask = (const int*)d_in[2];
    const float* W1   = (const float*)d_in[3];
    const float* b1   = (const float*)d_in[4];
    const float* W2   = (const float*)d_in[5];
    const float* b2   = (const float*)d_in[6];
    float* out = (float*)d_out;

    dim3 grid(Nv, Bv);   // (i, b): blocks sharing b are adjacent -> A[b] L2-hot

    if (ws_size >= (size_t)WS_NEED) {
        unsigned short* wpk = (unsigned short*)d_ws;
        unsigned short* apk = wpk + APK_OFF_SH;
        pack_w_kernel<<<4, 256, 0, stream>>>(W1, W2, wpk);
        pack_a_kernel<<<512, 256, 0, stream>>>(A, apk);
        nested_conv_mfma<true><<<grid, 256, 0, stream>>>(
            X, A, mask, W1, b1, W2, b2, wpk, apk, out);
    } else {
        nested_conv_mfma<false><<<grid, 256, 0, stream>>>(
            X, A, mask, W1, b1, W2, b2, nullptr, nullptr, out);
    }
}